// Round 4
// baseline (65.006 us; speedup 1.0000x reference)
//
#include <hip/hip_runtime.h>

// CRITICAL: hipcc defaults to -ffp-contract=fast; numpy/BLAS round every op
// separately. Kill contraction globally so our f32 arithmetic is op-by-op
// identical to the numpy reference.
#pragma clang fp contract(off)

#define N_PTS 8192
#define C_DIM 64
#define NQ (3 * N_PTS)            // 24576 query points
#define CHUNK 2048
#define NCHUNK (N_PTS / CHUNK)    // 4
#define GROUP 8                   // lanes per query
#define BLOCK 256
#define QPB (BLOCK / GROUP)       // 32 queries per block

// ---------------------------------------------------------------------------
// Kernel 1: bit-exact f32 replication of the reference's expanded-formula
// argmin:
//   sc  = rn( rn(cx^2) + rn(cy^2) )                (numpy elementwise+sum)
//   dot = fma(ay, cy, rn(ax*cx))                   (OpenBLAS sgemm K=2 chain)
//   d2  = rn( rn(sa + sc) - 2*dot )                (2*dot exact in f32)
// Then gather values[best_idx]. 8 lanes cooperate per query.
// ---------------------------------------------------------------------------
__global__ __launch_bounds__(BLOCK) void argmin_gather_kernel(
    const float* __restrict__ values,    // [N,64]
    const float* __restrict__ coords,    // [N,2]
    const float* __restrict__ spacing,   // [2]
    const float* __restrict__ shift,     // [2]
    float* __restrict__ out_values)      // [4N,64]
{
#pragma clang fp contract(off)
    __shared__ float4 cand[CHUNK];       // (cx, cy, sc, 0)

    const int tid    = threadIdx.x;
    const int lane_k = tid & (GROUP - 1);
    const int qi     = blockIdx.x * QPB + (tid / GROUP);   // [0, NQ)

    const float sx = spacing[0], sy = spacing[1];
    const float h0 = shift[0],   h1 = shift[1];

    const int which = qi / N_PTS;        // 0,1,2
    const int base  = qi - which * N_PTS;
    const float x = coords[2 * base + 0];
    const float y = coords[2 * base + 1];

    float nx, ny;
    if (which == 0)      { nx = x + sx; ny = y + sy; }
    else if (which == 1) { nx = x;      ny = y + sy; }
    else                 { nx = x + sx; ny = y; }

    const float ax = nx - h0;
    const float ay = ny - h1;
    const float sa = (ax * ax) + (ay * ay);   // contract off: rn(rn+rn)

    float best = INFINITY;
    int   bidx = 0;

    for (int ch = 0; ch < NCHUNK; ++ch) {
        const int cbase = ch * CHUNK;
        // stage chunk into LDS; sc = rn(rn(cx^2)+rn(cy^2)) — NO contraction
        for (int s = tid; s < CHUNK; s += BLOCK) {
            const float cx = coords[2 * (cbase + s) + 0];
            const float cy = coords[2 * (cbase + s) + 1];
            const float p0 = cx * cx;
            const float p1 = cy * cy;
            const float sc = p0 + p1;
            cand[s] = make_float4(cx, cy, sc, 0.0f);
        }
        __syncthreads();

        #pragma unroll 8
        for (int t = 0; t < CHUNK / GROUP; ++t) {
            const int jl = t * GROUP + lane_k;
            const float4 c = cand[jl];
            // BLAS sgemm K=2: acc = fma(a1,b1, fma(a0,b0,0)) = fma(ay,cy, rn(ax*cx))
            const float p  = ax * c.x;                 // separate rn mul
            const float dot = __builtin_fmaf(ay, c.y, p);
            const float t1 = sa + c.z;                 // rn(sa+sc)
            const float d2 = t1 - (2.0f * dot);        // 2*dot exact; one rn sub
            const int j = cbase + jl;
            if (d2 < best) { best = d2; bidx = j; }    // strict <: first-index ties
        }
        __syncthreads();
    }

    // combine across the 8-lane group; butterfly -> all lanes converge.
    // tie-break: lower d2 wins; equal d2 -> lower index (argmin semantics)
    #pragma unroll
    for (int m = 1; m < GROUP; m <<= 1) {
        const float od = __shfl_xor(best, m, 64);
        const int   oi = __shfl_xor(bidx, m, 64);
        if (od < best || (od == best && oi < bidx)) { best = od; bidx = oi; }
    }

    // gather the 64-float row: 8 lanes x 2 float4 each
    const float4* src = (const float4*)(values + (size_t)bidx * C_DIM);
    float4*       dst = (float4*)(out_values + (size_t)(N_PTS + qi) * C_DIM);
    dst[2 * lane_k + 0] = src[2 * lane_k + 0];
    dst[2 * lane_k + 1] = src[2 * lane_k + 1];
}

// ---------------------------------------------------------------------------
// Kernel 2: copy values -> out_values rows [0, N)
// ---------------------------------------------------------------------------
__global__ void copy_values_kernel(const float4* __restrict__ src,
                                   float4* __restrict__ dst, int n4)
{
    const int i = blockIdx.x * blockDim.x + threadIdx.x;
    if (i < n4) dst[i] = src[i];
}

// ---------------------------------------------------------------------------
// Kernel 3: out_coords rows [0, 4N): originals then the 3 shifted blocks
// ---------------------------------------------------------------------------
__global__ void coords_kernel(const float* __restrict__ coords,
                              const float* __restrict__ spacing,
                              float2* __restrict__ out_coords)
{
#pragma clang fp contract(off)
    const int r = blockIdx.x * blockDim.x + threadIdx.x;
    if (r >= 4 * N_PTS) return;
    float ox, oy;
    if (r < N_PTS) {
        ox = coords[2 * r + 0];
        oy = coords[2 * r + 1];
    } else {
        const int i     = r - N_PTS;
        const int which = i / N_PTS;
        const int b     = i - which * N_PTS;
        const float x = coords[2 * b + 0];
        const float y = coords[2 * b + 1];
        const float sx = spacing[0], sy = spacing[1];
        if (which == 0)      { ox = x + sx; oy = y + sy; }
        else if (which == 1) { ox = x;      oy = y + sy; }
        else                 { ox = x + sx; oy = y; }
    }
    out_coords[r] = make_float2(ox, oy);
}

extern "C" void kernel_launch(void* const* d_in, const int* in_sizes, int n_in,
                              void* d_out, int out_size, void* d_ws, size_t ws_size,
                              hipStream_t stream)
{
    const float* values  = (const float*)d_in[0];   // [8192,64]
    const float* coords  = (const float*)d_in[1];   // [8192,2]
    const float* spacing = (const float*)d_in[2];   // [2]
    const float* shift   = (const float*)d_in[3];   // [2]

    float* out_values = (float*)d_out;                          // [32768,64]
    float* out_coords = out_values + (size_t)4 * N_PTS * C_DIM; // [32768,2]

    // Kernel 2: copy original values (131072 float4s)
    {
        const int n4 = N_PTS * C_DIM / 4;
        copy_values_kernel<<<(n4 + 255) / 256, 256, 0, stream>>>(
            (const float4*)values, (float4*)out_values, n4);
    }

    // Kernel 3: all output coords
    {
        const int nr = 4 * N_PTS;
        coords_kernel<<<(nr + 255) / 256, 256, 0, stream>>>(
            coords, spacing, (float2*)out_coords);
    }

    // Kernel 1: argmin + gather for the 3N new rows
    {
        const int nblocks = NQ / QPB;   // 768
        argmin_gather_kernel<<<nblocks, BLOCK, 0, stream>>>(
            values, coords, spacing, shift, out_values);
    }
}

// Round 5
// 45.337 us; speedup vs baseline: 1.4339x; 1.4339x over previous
//
#include <hip/hip_runtime.h>

// numpy rounds every op separately — keep contraction off everywhere.
#pragma clang fp contract(off)

typedef float v2f __attribute__((ext_vector_type(2)));

#define N_PTS 8192
#define C_DIM 64
#define NQ (3 * N_PTS)           // 24576 queries
#define BLOCK 256
#define QB 1024                  // queries per block
#define QPT 16                   // queries per thread (8 float2 pairs)
#define NPAIR (QPT / 2)
#define NPART 32                 // candidate partitions
#define PART (N_PTS / NPART)     // 256 candidates per block
#define SLICE (PART / 4)         // 64 candidates per wave
#define NQBLK (NQ / QB)          // 24 query-blocks -> grid 24*32 = 768

// monotone f32 -> sortable u32 (handles tiny negative d2 from cancellation)
__device__ __forceinline__ unsigned int fsortkey(float f) {
    const unsigned int u = __float_as_uint(f);
    return (u & 0x80000000u) ? ~u : (u | 0x80000000u);
}

// ---------------------------------------------------------------------------
// Kernel 1: out_coords for all 4N rows + init the global key table to +inf.
// Runs first on the stream, so gkeys is re-initialized every call.
// ---------------------------------------------------------------------------
__global__ void coords_init_kernel(const float* __restrict__ coords,
                                   const float* __restrict__ spacing,
                                   float2* __restrict__ out_coords,
                                   unsigned long long* __restrict__ gkeys)
{
#pragma clang fp contract(off)
    const int r = blockIdx.x * blockDim.x + threadIdx.x;
    if (r >= 4 * N_PTS) return;
    if (r < NQ) gkeys[r] = ~0ULL;

    float ox, oy;
    if (r < N_PTS) {
        ox = coords[2 * r + 0];
        oy = coords[2 * r + 1];
    } else {
        const int i     = r - N_PTS;
        const int which = i / N_PTS;
        const int b     = i - which * N_PTS;
        const float x = coords[2 * b + 0];
        const float y = coords[2 * b + 1];
        const float sx = spacing[0], sy = spacing[1];
        if (which == 0)      { ox = x + sx; oy = y + sy; }
        else if (which == 1) { ox = x;      oy = y + sy; }
        else                 { ox = x + sx; oy = y; }
    }
    out_coords[r] = make_float2(ox, oy);
}

// ---------------------------------------------------------------------------
// Kernel 2: scan. Each block: 1024 queries x 256-candidate partition.
// Thread owns 16 queries (8 float2 pairs) in registers; each of the 4 waves
// scans a disjoint 64-candidate slice via broadcast LDS reads (uniform addr).
// Intra-block reduce in LDS, then one u64 atomicMin per (query, partition).
// Bit-exact d2: p=rn(ax*cx); dot=fma(ay,cy,p); t1=rn(sa+sc); d2=fma(-2,dot,t1)
// ---------------------------------------------------------------------------
__global__ __launch_bounds__(BLOCK) void nn_scan_kernel(
    const float* __restrict__ coords,
    const float* __restrict__ spacing,
    const float* __restrict__ shift,
    unsigned long long* __restrict__ gkeys)
{
#pragma clang fp contract(off)
    __shared__ float4 cand[PART];                       // 4 KB
    __shared__ unsigned long long klds[4][QB];          // 32 KB

    const int tid  = threadIdx.x;
    const int w    = tid >> 6;          // wave 0..3
    const int l    = tid & 63;          // lane
    const int bq   = blockIdx.x / NPART;    // query-block 0..23
    const int part = blockIdx.x % NPART;    // partition 0..31
    const int qbase = bq * QB;
    const int cbase = part * PART;

    // stage this block's 256 candidates (cx, cy, sc) into LDS
    {
        const float cx = coords[2 * (cbase + tid) + 0];
        const float cy = coords[2 * (cbase + tid) + 1];
        const float p0 = cx * cx;
        const float p1 = cy * cy;
        cand[tid] = make_float4(cx, cy, p0 + p1, 0.0f);
    }

    // query setup: which is uniform per block (QB divides N_PTS)
    const float sx = spacing[0], sy = spacing[1];
    const float h0 = shift[0],   h1 = shift[1];
    const int which = qbase / N_PTS;
    const int rbase = qbase - which * N_PTS;

    v2f ax[NPAIR], ay[NPAIR], sa[NPAIR], best[NPAIR];
    int bidx[QPT];

    #pragma unroll
    for (int p = 0; p < NPAIR; ++p) {
        const int b0 = rbase + l + 64 * (2 * p);
        const int b1 = rbase + l + 64 * (2 * p + 1);
        const float x0 = coords[2 * b0 + 0], y0 = coords[2 * b0 + 1];
        const float x1 = coords[2 * b1 + 0], y1 = coords[2 * b1 + 1];
        float nx0, ny0, nx1, ny1;
        if (which == 0)      { nx0 = x0 + sx; ny0 = y0 + sy; nx1 = x1 + sx; ny1 = y1 + sy; }
        else if (which == 1) { nx0 = x0;      ny0 = y0 + sy; nx1 = x1;      ny1 = y1 + sy; }
        else                 { nx0 = x0 + sx; ny0 = y0;      nx1 = x1 + sx; ny1 = y1; }
        const float ax0 = nx0 - h0, ay0 = ny0 - h1;
        const float ax1 = nx1 - h0, ay1 = ny1 - h1;
        ax[p].x = ax0; ax[p].y = ax1;
        ay[p].x = ay0; ay[p].y = ay1;
        sa[p].x = (ax0 * ax0) + (ay0 * ay0);
        sa[p].y = (ax1 * ax1) + (ay1 * ay1);
        best[p].x = INFINITY; best[p].y = INFINITY;
        bidx[2 * p] = 0; bidx[2 * p + 1] = 0;
    }
    __syncthreads();

    // scan this wave's 64-candidate slice (broadcast LDS reads)
    const int sbase = w * SLICE;
    const int jbase = cbase + sbase;
    #pragma unroll 8
    for (int t = 0; t < SLICE; ++t) {
        const float4 c = cand[sbase + t];
        const int j = jbase + t;
        #pragma unroll
        for (int p = 0; p < NPAIR; ++p) {
            const v2f pr  = ax[p] * (v2f)(c.x);                       // pk_mul
            const v2f dot = __builtin_elementwise_fma(ay[p], (v2f)(c.y), pr);
            const v2f t1  = sa[p] + (v2f)(c.z);                       // pk_add
            const v2f d2  = __builtin_elementwise_fma((v2f)(-2.0f), dot, t1);
            if (d2.x < best[p].x) { best[p].x = d2.x; bidx[2 * p]     = j; }
            if (d2.y < best[p].y) { best[p].y = d2.y; bidx[2 * p + 1] = j; }
        }
    }

    // pack (sortable d2, idx) keys -> LDS
    #pragma unroll
    for (int k = 0; k < QPT; ++k) {
        const float b = (k & 1) ? best[k / 2].y : best[k / 2].x;
        const unsigned long long key =
            ((unsigned long long)fsortkey(b) << 32) | (unsigned int)bidx[k];
        klds[w][l + 64 * k] = key;
    }
    __syncthreads();

    // reduce across 4 waves, one atomicMin per query
    #pragma unroll
    for (int k2 = 0; k2 < QB / BLOCK; ++k2) {
        const int q = tid + BLOCK * k2;
        unsigned long long m = klds[0][q];
        unsigned long long v1 = klds[1][q]; m = (v1 < m) ? v1 : m;
        unsigned long long v2 = klds[2][q]; m = (v2 < m) ? v2 : m;
        unsigned long long v3 = klds[3][q]; m = (v3 < m) ? v3 : m;
        atomicMin(&gkeys[qbase + q], m);
    }
}

// ---------------------------------------------------------------------------
// Kernel 3: write all 32768 out_values rows. Rows [0,N): copy; rows [N,4N):
// gather values[idx] with idx = low 32 bits of the winning key.
// 16 lanes per row, one float4 each.
// ---------------------------------------------------------------------------
__global__ __launch_bounds__(BLOCK) void gather_kernel(
    const float4* __restrict__ values,            // [N,16] float4
    const unsigned long long* __restrict__ gkeys, // [NQ]
    float4* __restrict__ out_values)              // [4N,16] float4
{
    const int t   = blockIdx.x * BLOCK + threadIdx.x;
    const int row = t >> 4;
    const int c4  = t & 15;
    int src;
    if (row < N_PTS) src = row;
    else             src = (int)(unsigned int)gkeys[row - N_PTS];
    out_values[row * 16 + c4] = values[src * 16 + c4];
}

extern "C" void kernel_launch(void* const* d_in, const int* in_sizes, int n_in,
                              void* d_out, int out_size, void* d_ws, size_t ws_size,
                              hipStream_t stream)
{
    const float* values  = (const float*)d_in[0];   // [8192,64]
    const float* coords  = (const float*)d_in[1];   // [8192,2]
    const float* spacing = (const float*)d_in[2];   // [2]
    const float* shift   = (const float*)d_in[3];   // [2]

    float* out_values = (float*)d_out;                          // [32768,64]
    float* out_coords = out_values + (size_t)4 * N_PTS * C_DIM; // [32768,2]

    unsigned long long* gkeys = (unsigned long long*)d_ws;      // 24576 * 8 B

    // 1) coords output + key-table init
    coords_init_kernel<<<(4 * N_PTS) / BLOCK, BLOCK, 0, stream>>>(
        coords, spacing, (float2*)out_coords, gkeys);

    // 2) argmin scan: 24 query-blocks x 32 partitions
    nn_scan_kernel<<<NQBLK * NPART, BLOCK, 0, stream>>>(
        coords, spacing, shift, gkeys);

    // 3) values copy + gather
    gather_kernel<<<(4 * N_PTS * 16) / BLOCK, BLOCK, 0, stream>>>(
        (const float4*)values, gkeys, (float4*)out_values);
}